// Round 3
// baseline (188.567 us; speedup 1.0000x reference)
//
#include <hip/hip_runtime.h>

// ---------------------------------------------------------------------------
// MinConv2dLSTM: 2x (3x3 conv -> minLSTM gates -> scan over S)
// B=4 S=16 H=W=32, layer0: Cin=32, layer1: Cin=64, gates Cout=256 (4x64)
// R2 resubmit: 2-phase double-buffered conv pipeline; vectorized scans.
// ---------------------------------------------------------------------------

typedef __bf16 bf16x8 __attribute__((ext_vector_type(8)));
typedef __bf16 bf16x4 __attribute__((ext_vector_type(4)));
typedef __bf16 bf16x2 __attribute__((ext_vector_type(2)));
typedef float f32x4 __attribute__((ext_vector_type(4)));

#define N_IMG 64      // B*S
#define HP 34         // padded H/W
#define COUT 256

__device__ __forceinline__ float sigf(float x) { return 1.0f / (1.0f + __expf(-x)); }

__device__ __forceinline__ void gload16(void* lds, const void* g) {
  __builtin_amdgcn_global_load_lds(
      (const __attribute__((address_space(1))) void*)g,
      (__attribute__((address_space(3))) void*)lds, 16, 0, 0);
}

// ---------------------------------------------------------------------------
// pack_x: x (64,32,32,32) NCHW fp32 -> xT padded NHWC bf16 (64,34,34,32)
// ---------------------------------------------------------------------------
__global__ __launch_bounds__(256) void pack_x_k(const float* __restrict__ x,
                                                __bf16* __restrict__ xT) {
  __shared__ float ls[32][33];
  const int n = blockIdx.x >> 5;
  const int h = blockIdx.x & 31;
  const int t = threadIdx.x;
  {
    const int w = t & 31, g4 = t >> 5;
    const float* src = x + (((size_t)n * 32) << 10) + (h << 5);
#pragma unroll
    for (int j = 0; j < 4; ++j) {
      int ci = g4 * 4 + j;
      ls[ci][w] = src[((size_t)ci << 10) + w];
    }
  }
  __syncthreads();
  {
    const int ci = t & 31, w4 = t >> 5;
    __bf16* dst = xT + ((size_t)(n * HP + h + 1) * HP + 1) * 32 + ci;
#pragma unroll
    for (int j = 0; j < 4; ++j) {
      int w = w4 * 4 + j;
      dst[w * 32] = (__bf16)ls[ci][w];
    }
  }
}

// ---------------------------------------------------------------------------
// pack_w: w (256,CIN,3,3) fp32 -> wT [co][kh*3+kw][ci] bf16
// ---------------------------------------------------------------------------
template <int CIN>
__global__ __launch_bounds__(256) void pack_w_k(const float* __restrict__ w,
                                                __bf16* __restrict__ wT) {
  int g = blockIdx.x * 256 + threadIdx.x;
  if (g >= 256 * 9 * CIN) return;
  int co = g / (9 * CIN);
  int r = g - co * 9 * CIN;
  int khkw = r / CIN;
  int ci = r - khkw * CIN;
  wT[g] = (__bf16)w[(size_t)(co * CIN + ci) * 9 + khkw];
}

// ---------------------------------------------------------------------------
// conv_gemm: implicit-GEMM 3x3 conv, bf16 MFMA 16x16x32, 2-phase dbuf.
// Block: 256 thr = 4 waves, tile 128(m=pixels) x 128(n=cout), 9 K-steps.
// Per step: STAGE(next) -> ds_read frags(cur) -> MFMA -> barrier (one/step).
// LDS [chunk16B][row] chunk-transposed: frag ds_read_b128 conflict-free,
// global_load_lds linear dest (1KB per call = one chunk x 64 rows).
// ---------------------------------------------------------------------------
template <int CIN, bool LAYER1>
__global__ __launch_bounds__(256, LAYER1 ? 2 : 4) void conv_gemm_k(
    const __bf16* __restrict__ xT,   // padded NHWC (64,34,34,CIN)
    const __bf16* __restrict__ wT,   // [256][9*CIN]
    const float* __restrict__ bias,  // [256]
    __bf16* __restrict__ gates) {
  constexpr int NKK = CIN / 32;     // MFMAs per frag pair per step
  constexpr int CHUNKS = CIN / 8;   // 16B chunks per row
  __shared__ bf16x8 lsA[2][CHUNKS * 128];
  __shared__ bf16x8 lsB[2][CHUNKS * 128];

  const int tid = threadIdx.x;
  const int lane = tid & 63;
  const int wid = tid >> 6;
  const int wr = wid >> 1, wc = wid & 1;

  const int bx = blockIdx.x;        // m-block: 8 per image
  const int by = blockIdx.y;        // co-block (2)
  const int n = bx >> 3;
  const int h0 = (bx & 7) << 2;     // 4 image rows per block
  const int co0 = by << 7;

  f32x4 acc[4][4] = {};
  const size_t wrow = (size_t)9 * CIN;

  auto stage = [&](int buf, int t) {
    const int kh = t / 3;
    const int kw = t - kh * 3;
#pragma unroll
    for (int c = wid; c < 2 * CHUNKS; c += 4) {
      const int chunk = c >> 1;
      const int pix = ((c & 1) << 6) + lane;
      const int hh = h0 + (pix >> 5) + kh;
      const int ww = (pix & 31) + kw;
      gload16((void*)(&lsA[buf][c * 64]),
              (const void*)(xT + ((size_t)(n * HP + hh) * HP + ww) * CIN + chunk * 8));
    }
#pragma unroll
    for (int c = wid; c < 2 * CHUNKS; c += 4) {
      const int chunk = c >> 1;
      const int row = ((c & 1) << 6) + lane;
      gload16((void*)(&lsB[buf][c * 64]),
              (const void*)(wT + (size_t)(co0 + row) * wrow + t * CIN + chunk * 8));
    }
  };

  stage(0, 0);
  __syncthreads();          // vmcnt(0) drain + barrier: buf0 ready
  int cur = 0;
  for (int t = 0; t < 9; ++t) {
    if (t < 8) stage(cur ^ 1, t + 1);   // issue next-tile loads FIRST
#pragma unroll
    for (int kk = 0; kk < NKK; ++kk) {
      const int ca = kk * 4 + (lane >> 4);
      bf16x8 af[4], wf[4];
#pragma unroll
      for (int mi = 0; mi < 4; ++mi)
        af[mi] = lsA[cur][ca * 128 + wr * 64 + mi * 16 + (lane & 15)];
#pragma unroll
      for (int ni = 0; ni < 4; ++ni)
        wf[ni] = lsB[cur][ca * 128 + wc * 64 + ni * 16 + (lane & 15)];
#pragma unroll
      for (int mi = 0; mi < 4; ++mi)
#pragma unroll
        for (int ni = 0; ni < 4; ++ni) {
          if constexpr (!LAYER1)
            acc[mi][ni] = __builtin_amdgcn_mfma_f32_16x16x32_bf16(
                af[mi], wf[ni], acc[mi][ni], 0, 0, 0);
          else
            acc[mi][ni] = __builtin_amdgcn_mfma_f32_16x16x32_bf16(
                wf[ni], af[mi], acc[mi][ni], 0, 0, 0);
        }
    }
    __syncthreads();        // drains vmcnt(0) (stage done) + lgkm, one/step
    cur ^= 1;
  }

  // epilogue: C/D map col=lane&15, row=(lane>>4)*4+r
#pragma unroll
  for (int mi = 0; mi < 4; ++mi)
#pragma unroll
    for (int ni = 0; ni < 4; ++ni)
#pragma unroll
      for (int r = 0; r < 4; ++r) {
        if constexpr (!LAYER1) {
          const int m_loc = wr * 64 + mi * 16 + ((lane >> 4) << 2) + r;
          const int co = co0 + wc * 64 + ni * 16 + (lane & 15);
          const size_t m = (size_t)bx * 128 + m_loc;
          gates[m * 256 + co] = (__bf16)(acc[mi][ni][r] + bias[co]);
        } else {
          const int co = co0 + wc * 64 + ni * 16 + ((lane >> 4) << 2) + r;
          const int m_loc = wr * 64 + mi * 16 + (lane & 15);
          const int m = bx * 128 + m_loc;
          const int nimg = m >> 10, p = m & 1023;
          gates[((size_t)nimg * 256 + co) * 1024 + p] =
              (__bf16)(acc[mi][ni][r] + bias[co]);
        }
      }
}

// ---------------------------------------------------------------------------
// scan0: gates [m][256] bf16 -> h0T padded NHWC bf16 (64,34,34,64)
// thread = (b, p, c-pair): bf16x2 loads/stores (4B/lane). 512 blocks x 256.
// ---------------------------------------------------------------------------
__global__ __launch_bounds__(256) void scan0_k(const __bf16* __restrict__ gates,
                                               __bf16* __restrict__ h0T) {
  const int g = blockIdx.x * 256 + threadIdx.x;  // 4*1024*32
  const int c = (g & 31) * 2;
  const int p = (g >> 5) & 1023;
  const int b = g >> 15;
  const int h = p >> 5, w = p & 31;
  float c0 = 0.5f, c1 = 0.5f;
#pragma unroll 4
  for (int s = 0; s < 16; ++s) {
    const size_t base = ((size_t)((b * 16 + s) * 1024 + p)) * 256 + c;
    const bf16x2* gp = reinterpret_cast<const bf16x2*>(gates + base);
    const bf16x2 ig2 = gp[0], fg2 = gp[32], og2 = gp[64], cd2 = gp[96];
    bf16x2 hv2;
#pragma unroll
    for (int j = 0; j < 2; ++j) {
      const float it = sigf((float)ig2[j]), ft = sigf((float)fg2[j]);
      const float inv = 1.0f / (it + ft);
      const float cd_ = (float)cd2[j];
      const float gc = (cd_ >= 0.0f) ? (cd_ + 0.5f) : sigf(cd_);
      float& cst = j ? c1 : c0;
      cst = (ft * inv) * cst + (it * inv) * gc;
      hv2[j] = (__bf16)(sigf((float)og2[j]) * cst);
    }
    *reinterpret_cast<bf16x2*>(
        h0T + ((size_t)((b * 16 + s) * HP + h + 1) * HP + (w + 1)) * 64 + c) = hv2;
  }
}

// ---------------------------------------------------------------------------
// scan1: gates [n][256][1024] bf16 -> out fp32 (B,S,64,32,32)
// thread = (b, c, 4 pixels): bf16x4 loads (8B), float4 stores. 256 blocks.
// ---------------------------------------------------------------------------
__global__ __launch_bounds__(256) void scan1_k(const __bf16* __restrict__ gates,
                                               float* __restrict__ out) {
  const int g = blockIdx.x * 256 + threadIdx.x;  // 4*64*256
  const int p0 = (g & 255) * 4;
  const int c = (g >> 8) & 63;
  const int b = g >> 14;
  float cst[4] = {0.5f, 0.5f, 0.5f, 0.5f};
#pragma unroll 2
  for (int s = 0; s < 16; ++s) {
    const size_t base = ((size_t)(b * 16 + s) * 256 + c) * 1024 + p0;
    const bf16x4 ig4 = *reinterpret_cast<const bf16x4*>(gates + base);
    const bf16x4 fg4 = *reinterpret_cast<const bf16x4*>(gates + base + 64 * 1024);
    const bf16x4 og4 = *reinterpret_cast<const bf16x4*>(gates + base + 128 * 1024);
    const bf16x4 cd4 = *reinterpret_cast<const bf16x4*>(gates + base + 192 * 1024);
    f32x4 hv;
#pragma unroll
    for (int j = 0; j < 4; ++j) {
      const float it = sigf((float)ig4[j]), ft = sigf((float)fg4[j]);
      const float inv = 1.0f / (it + ft);
      const float cd_ = (float)cd4[j];
      const float gc = (cd_ >= 0.0f) ? (cd_ + 0.5f) : sigf(cd_);
      cst[j] = (ft * inv) * cst[j] + (it * inv) * gc;
      hv[j] = sigf((float)og4[j]) * cst[j];
    }
    *reinterpret_cast<f32x4*>(
        out + ((size_t)((b * 16 + s) * 64 + c)) * 1024 + p0) = hv;
  }
}

// ---------------------------------------------------------------------------
extern "C" void kernel_launch(void* const* d_in, const int* in_sizes, int n_in,
                              void* d_out, int out_size, void* d_ws,
                              size_t ws_size, hipStream_t stream) {
  const float* x = (const float*)d_in[0];   // (4,16,32,32,32)
  const float* w0 = (const float*)d_in[1];  // (256,32,3,3)
  const float* b0 = (const float*)d_in[2];  // (256)
  const float* w1 = (const float*)d_in[3];  // (256,64,3,3)
  const float* b1 = (const float*)d_in[4];  // (256)
  float* out = (float*)d_out;               // (4,16,64,32,32)

  char* ws = (char*)d_ws;
  const size_t XT_BYTES = (size_t)N_IMG * HP * HP * 32 * 2;
  const size_t H0_BYTES = (size_t)N_IMG * HP * HP * 64 * 2;
  const size_t W0T_BYTES = (size_t)256 * 9 * 32 * 2;
  const size_t W1T_BYTES = (size_t)256 * 9 * 64 * 2;
  __bf16* xT = (__bf16*)ws;
  __bf16* h0T = (__bf16*)(ws + XT_BYTES);
  __bf16* w0T = (__bf16*)(ws + XT_BYTES + H0_BYTES);
  __bf16* w1T = (__bf16*)(ws + XT_BYTES + H0_BYTES + W0T_BYTES);
  __bf16* gates = (__bf16*)(ws + XT_BYTES + H0_BYTES + W0T_BYTES + W1T_BYTES);
  (void)ws_size; (void)n_in; (void)in_sizes; (void)out_size;

  hipMemsetAsync(xT, 0, XT_BYTES, stream);
  hipMemsetAsync(h0T, 0, H0_BYTES, stream);

  pack_x_k<<<N_IMG * 32, 256, 0, stream>>>(x, xT);
  pack_w_k<32><<<(256 * 9 * 32 + 255) / 256, 256, 0, stream>>>(w0, w0T);
  pack_w_k<64><<<(256 * 9 * 64 + 255) / 256, 256, 0, stream>>>(w1, w1T);

  // layer 0
  conv_gemm_k<32, false><<<dim3(512, 2), 256, 0, stream>>>(xT, w0T, b0, gates);
  scan0_k<<<512, 256, 0, stream>>>(gates, h0T);
  // layer 1
  conv_gemm_k<64, true><<<dim3(512, 2), 256, 0, stream>>>(h0T, w1T, b1, gates);
  scan1_k<<<256, 256, 0, stream>>>(gates, out);
}

// Round 10
// 165.663 us; speedup vs baseline: 1.1383x; 1.1383x over previous
//
#include <hip/hip_runtime.h>

// ---------------------------------------------------------------------------
// MinConv2dLSTM: 2x (3x3 conv -> minLSTM gates -> scan over S)
// B=4 S=16 H=W=32, layer0: Cin=32, layer1: Cin=64, gates Cout=256 (4x64)
// R4 resubmit (x6): A-resident conv (stage 6x34xCIN patch once, chunk-major;
//     9-tap K-loop reads A via immediate offsets; only B dbuf per tap).
// ---------------------------------------------------------------------------

typedef __bf16 bf16x8 __attribute__((ext_vector_type(8)));
typedef __bf16 bf16x4 __attribute__((ext_vector_type(4)));
typedef __bf16 bf16x2 __attribute__((ext_vector_type(2)));
typedef float f32x4 __attribute__((ext_vector_type(4)));

#define N_IMG 64      // B*S
#define HP 34         // padded H/W
#define COUT 256

__device__ __forceinline__ float sigf(float x) { return 1.0f / (1.0f + __expf(-x)); }

__device__ __forceinline__ void gload16(void* lds, const void* g) {
  __builtin_amdgcn_global_load_lds(
      (const __attribute__((address_space(1))) void*)g,
      (__attribute__((address_space(3))) void*)lds, 16, 0, 0);
}

// ---------------------------------------------------------------------------
// pack_x: x (64,32,32,32) NCHW fp32 -> xT padded NHWC bf16 (64,34,34,32)
// ---------------------------------------------------------------------------
__global__ __launch_bounds__(256) void pack_x_k(const float* __restrict__ x,
                                                __bf16* __restrict__ xT) {
  __shared__ float ls[32][33];
  const int n = blockIdx.x >> 5;
  const int h = blockIdx.x & 31;
  const int t = threadIdx.x;
  {
    const int w = t & 31, g4 = t >> 5;
    const float* src = x + (((size_t)n * 32) << 10) + (h << 5);
#pragma unroll
    for (int j = 0; j < 4; ++j) {
      int ci = g4 * 4 + j;
      ls[ci][w] = src[((size_t)ci << 10) + w];
    }
  }
  __syncthreads();
  {
    const int ci = t & 31, w4 = t >> 5;
    __bf16* dst = xT + ((size_t)(n * HP + h + 1) * HP + 1) * 32 + ci;
#pragma unroll
    for (int j = 0; j < 4; ++j) {
      int w = w4 * 4 + j;
      dst[w * 32] = (__bf16)ls[ci][w];
    }
  }
}

// ---------------------------------------------------------------------------
// pack_w: w (256,CIN,3,3) fp32 -> wT [co][kh*3+kw][ci] bf16
// ---------------------------------------------------------------------------
template <int CIN>
__global__ __launch_bounds__(256) void pack_w_k(const float* __restrict__ w,
                                                __bf16* __restrict__ wT) {
  int g = blockIdx.x * 256 + threadIdx.x;
  if (g >= 256 * 9 * CIN) return;
  int co = g / (9 * CIN);
  int r = g - co * 9 * CIN;
  int khkw = r / CIN;
  int ci = r - khkw * CIN;
  wT[g] = (__bf16)w[(size_t)(co * CIN + ci) * 9 + khkw];
}

// ---------------------------------------------------------------------------
// conv_gemm: implicit-GEMM 3x3 conv, bf16 MFMA 16x16x32, A-resident.
// Block: 256 thr = 4 waves, tile 128(m=pixels: 4 image rows) x 128(n=cout).
// lsA: chunk-major [CHUNKS][6*34] bf16x8 — staged ONCE, read by all 9 taps
//      at immediate offsets (tap adds (kh*34+kw) slots). <=2-way conflicts.
// lsB: [2][CHUNKS][128] bf16x8 — weights, global_load_lds dbuf, 1 tap ahead.
// One __syncthreads per tap (B-buffer flip).
// ---------------------------------------------------------------------------
template <int CIN, bool LAYER1>
__global__ __launch_bounds__(256, 2) void conv_gemm_k(
    const __bf16* __restrict__ xT,   // padded NHWC (64,34,34,CIN)
    const __bf16* __restrict__ wT,   // [256][9*CIN]
    const float* __restrict__ bias,  // [256]
    __bf16* __restrict__ gates) {
  constexpr int NKK = CIN / 32;     // MFMAs per frag pair per tap
  constexpr int CHUNKS = CIN / 8;   // 16B ci-chunks per pixel
  constexpr int PLANE = 204;        // 6*34 pixel slots per chunk-plane
  __shared__ bf16x8 lsA[CHUNKS * PLANE];
  __shared__ bf16x8 lsB[2][CHUNKS * 128];

  const int tid = threadIdx.x;
  const int lane = tid & 63;
  const int wid = tid >> 6;
  const int wr = wid >> 1, wc = wid & 1;
  const int g = lane >> 4;          // ci-chunk group
  const int li = lane & 15;         // m / co within fragment

  const int bx = blockIdx.x;        // m-block: 8 per image
  const int by = blockIdx.y;        // co-block (2)
  const int n = bx >> 3;
  const int h0 = (bx & 7) << 2;     // first padded row of the 4 image rows
  const int co0 = by << 7;

  f32x4 acc[4][4] = {};
  const size_t wrow = (size_t)9 * CIN;

  // --- stage A once: padded rows h0..h0+5, cols 0..33, all ci (chunk-major)
  for (int gi = tid; gi < CHUNKS * PLANE; gi += 256) {
    const int ch = gi & (CHUNKS - 1);
    const int pos = gi / CHUNKS;          // r*34 + w
    const int r = pos / 34;
    const int w = pos - r * 34;
    lsA[ch * PLANE + pos] = *reinterpret_cast<const bf16x8*>(
        xT + ((size_t)(n * HP + h0 + r) * HP + w) * CIN + ch * 8);
  }

  // per-(mi) pixel slot within the A patch (tap-invariant)
  int posm[4];
#pragma unroll
  for (int mi = 0; mi < 4; ++mi) {
    const int m = wr * 64 + mi * 16 + li;
    posm[mi] = (m >> 5) * 34 + (m & 31);
  }

  auto stageB = [&](int buf, int t) {
#pragma unroll
    for (int c = wid; c < 2 * CHUNKS; c += 4) {
      const int chunk = c >> 1;
      const int row = ((c & 1) << 6) + lane;
      gload16((void*)(&lsB[buf][c * 64]),
              (const void*)(wT + (size_t)(co0 + row) * wrow + t * CIN + chunk * 8));
    }
  };

  stageB(0, 0);
  __syncthreads();          // lsA (ds_writes) + lsB[0] (vmcnt) ready
  int cur = 0;
#pragma unroll
  for (int t = 0; t < 9; ++t) {
    const int kh = t / 3;
    const int kw = t - kh * 3;
    const int tapoff = kh * 34 + kw;      // constant per unrolled tap
    if (t < 8) stageB(cur ^ 1, t + 1);
#pragma unroll
    for (int kk = 0; kk < NKK; ++kk) {
      const int ca = kk * 4 + g;
      bf16x8 af[4], wf[4];
#pragma unroll
      for (int mi = 0; mi < 4; ++mi)
        af[mi] = lsA[ca * PLANE + posm[mi] + tapoff];
#pragma unroll
      for (int ni = 0; ni < 4; ++ni)
        wf[ni] = lsB[cur][ca * 128 + wc * 64 + ni * 16 + li];
#pragma unroll
      for (int mi = 0; mi < 4; ++mi)
#pragma unroll
        for (int ni = 0; ni < 4; ++ni) {
          if constexpr (!LAYER1)
            acc[mi][ni] = __builtin_amdgcn_mfma_f32_16x16x32_bf16(
                af[mi], wf[ni], acc[mi][ni], 0, 0, 0);
          else
            acc[mi][ni] = __builtin_amdgcn_mfma_f32_16x16x32_bf16(
                wf[ni], af[mi], acc[mi][ni], 0, 0, 0);
        }
    }
    __syncthreads();        // B-buffer flip
    cur ^= 1;
  }

  // epilogue: C/D map col=lane&15, row=(lane>>4)*4+r
#pragma unroll
  for (int mi = 0; mi < 4; ++mi)
#pragma unroll
    for (int ni = 0; ni < 4; ++ni)
#pragma unroll
      for (int r = 0; r < 4; ++r) {
        if constexpr (!LAYER1) {
          const int m_loc = wr * 64 + mi * 16 + (g << 2) + r;
          const int co = co0 + wc * 64 + ni * 16 + li;
          const size_t m = (size_t)bx * 128 + m_loc;
          gates[m * 256 + co] = (__bf16)(acc[mi][ni][r] + bias[co]);
        } else {
          const int co = co0 + wc * 64 + ni * 16 + (g << 2) + r;
          const int m_loc = wr * 64 + mi * 16 + li;
          const int m = bx * 128 + m_loc;
          const int nimg = m >> 10, p = m & 1023;
          gates[((size_t)nimg * 256 + co) * 1024 + p] =
              (__bf16)(acc[mi][ni][r] + bias[co]);
        }
      }
}

// ---------------------------------------------------------------------------
// scan0: gates [m][256] bf16 -> h0T padded NHWC bf16 (64,34,34,64)
// thread = (b, p, c-quad): bf16x4 loads/stores (8B/lane). 256 blocks x 256.
// ---------------------------------------------------------------------------
__global__ __launch_bounds__(256) void scan0_k(const __bf16* __restrict__ gates,
                                               __bf16* __restrict__ h0T) {
  const int g = blockIdx.x * 256 + threadIdx.x;  // 4*1024*16
  const int c = (g & 15) * 4;
  const int p = (g >> 4) & 1023;
  const int b = g >> 14;
  const int h = p >> 5, w = p & 31;
  float cst[4] = {0.5f, 0.5f, 0.5f, 0.5f};
#pragma unroll 4
  for (int s = 0; s < 16; ++s) {
    const size_t base = ((size_t)((b * 16 + s) * 1024 + p)) * 256 + c;
    const bf16x4* gp = reinterpret_cast<const bf16x4*>(gates + base);
    const bf16x4 ig4 = gp[0], fg4 = gp[16], og4 = gp[32], cd4 = gp[48];
    bf16x4 hv4;
#pragma unroll
    for (int j = 0; j < 4; ++j) {
      const float it = sigf((float)ig4[j]), ft = sigf((float)fg4[j]);
      const float inv = 1.0f / (it + ft);
      const float cd_ = (float)cd4[j];
      const float gc = (cd_ >= 0.0f) ? (cd_ + 0.5f) : sigf(cd_);
      cst[j] = (ft * inv) * cst[j] + (it * inv) * gc;
      hv4[j] = (__bf16)(sigf((float)og4[j]) * cst[j]);
    }
    *reinterpret_cast<bf16x4*>(
        h0T + ((size_t)((b * 16 + s) * HP + h + 1) * HP + (w + 1)) * 64 + c) = hv4;
  }
}

// ---------------------------------------------------------------------------
// scan1: gates [n][256][1024] bf16 -> out fp32 (B,S,64,32,32)
// thread = (b, c, 4 pixels): bf16x4 loads (8B), float4 stores. 256 blocks.
// ---------------------------------------------------------------------------
__global__ __launch_bounds__(256) void scan1_k(const __bf16* __restrict__ gates,
                                               float* __restrict__ out) {
  const int g = blockIdx.x * 256 + threadIdx.x;  // 4*64*256
  const int p0 = (g & 255) * 4;
  const int c = (g >> 8) & 63;
  const int b = g >> 14;
  float cst[4] = {0.5f, 0.5f, 0.5f, 0.5f};
#pragma unroll 2
  for (int s = 0; s < 16; ++s) {
    const size_t base = ((size_t)(b * 16 + s) * 256 + c) * 1024 + p0;
    const bf16x4 ig4 = *reinterpret_cast<const bf16x4*>(gates + base);
    const bf16x4 fg4 = *reinterpret_cast<const bf16x4*>(gates + base + 64 * 1024);
    const bf16x4 og4 = *reinterpret_cast<const bf16x4*>(gates + base + 128 * 1024);
    const bf16x4 cd4 = *reinterpret_cast<const bf16x4*>(gates + base + 192 * 1024);
    f32x4 hv;
#pragma unroll
    for (int j = 0; j < 4; ++j) {
      const float it = sigf((float)ig4[j]), ft = sigf((float)fg4[j]);
      const float inv = 1.0f / (it + ft);
      const float cd_ = (float)cd4[j];
      const float gc = (cd_ >= 0.0f) ? (cd_ + 0.5f) : sigf(cd_);
      cst[j] = (ft * inv) * cst[j] + (it * inv) * gc;
      hv[j] = sigf((float)og4[j]) * cst[j];
    }
    *reinterpret_cast<f32x4*>(
        out + ((size_t)((b * 16 + s) * 64 + c)) * 1024 + p0) = hv;
  }
}

// ---------------------------------------------------------------------------
extern "C" void kernel_launch(void* const* d_in, const int* in_sizes, int n_in,
                              void* d_out, int out_size, void* d_ws,
                              size_t ws_size, hipStream_t stream) {
  const float* x = (const float*)d_in[0];   // (4,16,32,32,32)
  const float* w0 = (const float*)d_in[1];  // (256,32,3,3)
  const float* b0 = (const float*)d_in[2];  // (256)
  const float* w1 = (const float*)d_in[3];  // (256,64,3,3)
  const float* b1 = (const float*)d_in[4];  // (256)
  float* out = (float*)d_out;               // (4,16,64,32,32)

  char* ws = (char*)d_ws;
  const size_t XT_BYTES = (size_t)N_IMG * HP * HP * 32 * 2;
  const size_t H0_BYTES = (size_t)N_IMG * HP * HP * 64 * 2;
  const size_t W0T_BYTES = (size_t)256 * 9 * 32 * 2;
  const size_t W1T_BYTES = (size_t)256 * 9 * 64 * 2;
  __bf16* xT = (__bf16*)ws;
  __bf16* h0T = (__bf16*)(ws + XT_BYTES);
  __bf16* w0T = (__bf16*)(ws + XT_BYTES + H0_BYTES);
  __bf16* w1T = (__bf16*)(ws + XT_BYTES + H0_BYTES + W0T_BYTES);
  __bf16* gates = (__bf16*)(ws + XT_BYTES + H0_BYTES + W0T_BYTES + W1T_BYTES);
  (void)ws_size; (void)n_in; (void)in_sizes; (void)out_size;

  hipMemsetAsync(xT, 0, XT_BYTES, stream);
  hipMemsetAsync(h0T, 0, H0_BYTES, stream);

  pack_x_k<<<N_IMG * 32, 256, 0, stream>>>(x, xT);
  pack_w_k<32><<<(256 * 9 * 32 + 255) / 256, 256, 0, stream>>>(w0, w0T);
  pack_w_k<64><<<(256 * 9 * 64 + 255) / 256, 256, 0, stream>>>(w1, w1T);

  // layer 0
  conv_gemm_k<32, false><<<dim3(512, 2), 256, 0, stream>>>(xT, w0T, b0, gates);
  scan0_k<<<256, 256, 0, stream>>>(gates, h0T);
  // layer 1
  conv_gemm_k<64, true><<<dim3(512, 2), 256, 0, stream>>>(h0T, w1T, b1, gates);
  scan1_k<<<256, 256, 0, stream>>>(gates, out);
}

// Round 11
// 163.443 us; speedup vs baseline: 1.1537x; 1.0136x over previous
//
#include <hip/hip_runtime.h>

// ---------------------------------------------------------------------------
// MinConv2dLSTM: 2x (3x3 conv -> minLSTM gates -> scan over S)
// B=4 S=16 H=W=32, layer0: Cin=32, layer1: Cin=64, gates Cout=256 (4x64)
// R11: counted-vmcnt conv pipeline (T4): 3-buffer lsB rotation, depth-2
//      prefetch, raw s_barrier + vmcnt(G) (never 0 in steady state).
// ---------------------------------------------------------------------------

typedef __bf16 bf16x8 __attribute__((ext_vector_type(8)));
typedef __bf16 bf16x4 __attribute__((ext_vector_type(4)));
typedef float f32x4 __attribute__((ext_vector_type(4)));

#define N_IMG 64      // B*S
#define HP 34         // padded H/W
#define COUT 256

__device__ __forceinline__ float sigf(float x) { return 1.0f / (1.0f + __expf(-x)); }

__device__ __forceinline__ void gload16(void* lds, const void* g) {
  __builtin_amdgcn_global_load_lds(
      (const __attribute__((address_space(1))) void*)g,
      (__attribute__((address_space(3))) void*)lds, 16, 0, 0);
}

template <int N> __device__ __forceinline__ void waitbar() {
  asm volatile("s_waitcnt vmcnt(%0)" :: "n"(N) : "memory");
  __builtin_amdgcn_s_barrier();
  __builtin_amdgcn_sched_barrier(0);
}

// ---------------------------------------------------------------------------
// pack_x: x (64,32,32,32) NCHW fp32 -> xT padded NHWC bf16 (64,34,34,32)
// ---------------------------------------------------------------------------
__global__ __launch_bounds__(256) void pack_x_k(const float* __restrict__ x,
                                                __bf16* __restrict__ xT) {
  __shared__ float ls[32][33];
  const int n = blockIdx.x >> 5;
  const int h = blockIdx.x & 31;
  const int t = threadIdx.x;
  {
    const int w = t & 31, g4 = t >> 5;
    const float* src = x + (((size_t)n * 32) << 10) + (h << 5);
#pragma unroll
    for (int j = 0; j < 4; ++j) {
      int ci = g4 * 4 + j;
      ls[ci][w] = src[((size_t)ci << 10) + w];
    }
  }
  __syncthreads();
  {
    const int ci = t & 31, w4 = t >> 5;
    __bf16* dst = xT + ((size_t)(n * HP + h + 1) * HP + 1) * 32 + ci;
#pragma unroll
    for (int j = 0; j < 4; ++j) {
      int w = w4 * 4 + j;
      dst[w * 32] = (__bf16)ls[ci][w];
    }
  }
}

// ---------------------------------------------------------------------------
// pack_w: w (256,CIN,3,3) fp32 -> wT [co][kh*3+kw][ci] bf16
// ---------------------------------------------------------------------------
template <int CIN>
__global__ __launch_bounds__(256) void pack_w_k(const float* __restrict__ w,
                                                __bf16* __restrict__ wT) {
  int g = blockIdx.x * 256 + threadIdx.x;
  if (g >= 256 * 9 * CIN) return;
  int co = g / (9 * CIN);
  int r = g - co * 9 * CIN;
  int khkw = r / CIN;
  int ci = r - khkw * CIN;
  wT[g] = (__bf16)w[(size_t)(co * CIN + ci) * 9 + khkw];
}

// ---------------------------------------------------------------------------
// conv_gemm: implicit-GEMM 3x3 conv, bf16 MFMA 16x16x32, A-resident,
// counted-vmcnt weight pipeline.
// Block: 256 thr = 4 waves, tile 128(m=pixels: 4 image rows) x 128(n=cout).
// lsA: chunk-major [CHUNKS][6*34] bf16x8 — staged ONCE, all 9 taps read it
//      at tap-constant immediate offsets. <=2-way bank conflicts.
// lsB: [3][CHUNKS][128] bf16x8 — weights, global_load_lds, stage depth 2,
//      raw s_barrier + vmcnt(G) per tap (G loads/wave stay in flight).
// ---------------------------------------------------------------------------
template <int CIN, bool LAYER1>
__global__ __launch_bounds__(256, 2) void conv_gemm_k(
    const __bf16* __restrict__ xT,   // padded NHWC (64,34,34,CIN)
    const __bf16* __restrict__ wT,   // [256][9*CIN]
    const float* __restrict__ bias,  // [256]
    __bf16* __restrict__ gates) {
  constexpr int NKK = CIN / 32;     // MFMA k-groups per tap
  constexpr int CHUNKS = CIN / 8;   // 16B ci-chunks per pixel
  constexpr int G = (2 * CHUNKS) / 4;  // gloads per wave per tap (64:4, 32:2)
  constexpr int PLANE = 204;        // 6*34 pixel slots per chunk-plane
  __shared__ bf16x8 lsA[CHUNKS * PLANE];
  __shared__ bf16x8 lsB[3][CHUNKS * 128];

  const int tid = threadIdx.x;
  const int lane = tid & 63;
  const int wid = tid >> 6;
  const int wr = wid >> 1, wc = wid & 1;
  const int g = lane >> 4;          // ci-chunk group
  const int li = lane & 15;         // m / co within fragment

  const int bx = blockIdx.x;        // m-block: 8 per image
  const int by = blockIdx.y;        // co-block (2)
  const int n = bx >> 3;
  const int h0 = (bx & 7) << 2;     // first padded row of the 4 image rows
  const int co0 = by << 7;

  f32x4 acc[4][4] = {};
  const size_t wrow = (size_t)9 * CIN;

  // --- stage A once: padded rows h0..h0+5, cols 0..33, all ci (chunk-major)
  for (int gi = tid; gi < CHUNKS * PLANE; gi += 256) {
    const int ch = gi & (CHUNKS - 1);
    const int pos = gi / CHUNKS;          // r*34 + w
    const int r = pos / 34;
    const int w = pos - r * 34;
    lsA[ch * PLANE + pos] = *reinterpret_cast<const bf16x8*>(
        xT + ((size_t)(n * HP + h0 + r) * HP + w) * CIN + ch * 8);
  }

  // per-(mi) pixel slot within the A patch (tap-invariant)
  int posm[4];
#pragma unroll
  for (int mi = 0; mi < 4; ++mi) {
    const int m = wr * 64 + mi * 16 + li;
    posm[mi] = (m >> 5) * 34 + (m & 31);
  }

  auto stageB = [&](int buf, int t) {
#pragma unroll
    for (int c = wid; c < 2 * CHUNKS; c += 4) {
      const int chunk = c >> 1;
      const int row = ((c & 1) << 6) + lane;
      gload16((void*)(&lsB[buf][c * 64]),
              (const void*)(wT + (size_t)(co0 + row) * wrow + t * CIN + chunk * 8));
    }
  };

  auto compute = [&](int t) {
    const int kh = t / 3;
    const int kw = t - kh * 3;
    const int tapoff = kh * 34 + kw;      // constant per unrolled tap
    const int buf = t % 3;
#pragma unroll
    for (int kk = 0; kk < NKK; ++kk) {
      const int ca = kk * 4 + g;
      bf16x8 af[4], wf[4];
#pragma unroll
      for (int mi = 0; mi < 4; ++mi)
        af[mi] = lsA[ca * PLANE + posm[mi] + tapoff];
#pragma unroll
      for (int ni = 0; ni < 4; ++ni)
        wf[ni] = lsB[buf][ca * 128 + wc * 64 + ni * 16 + li];
#pragma unroll
      for (int mi = 0; mi < 4; ++mi)
#pragma unroll
        for (int ni = 0; ni < 4; ++ni) {
          if constexpr (!LAYER1)
            acc[mi][ni] = __builtin_amdgcn_mfma_f32_16x16x32_bf16(
                af[mi], wf[ni], acc[mi][ni], 0, 0, 0);
          else
            acc[mi][ni] = __builtin_amdgcn_mfma_f32_16x16x32_bf16(
                wf[ni], af[mi], acc[mi][ni], 0, 0, 0);
        }
    }
  };

  // prologue: A-patch + taps 0,1 in flight; wait tap0 (leave tap1's G out)
  stageB(0, 0);
  stageB(1, 1);
  asm volatile("s_waitcnt vmcnt(%0) lgkmcnt(0)" :: "n"(G) : "memory");
  __builtin_amdgcn_s_barrier();
  __builtin_amdgcn_sched_barrier(0);

  // steady state: stage t+2, compute t, wait leaving G in flight
#pragma unroll
  for (int t = 0; t < 7; ++t) {
    stageB((t + 2) % 3, t + 2);
    compute(t);
    waitbar<G>();          // taps <= t+1 complete; tap t+2's G may remain
  }
  compute(7);
  waitbar<0>();            // drain tap 8
  compute(8);

  // epilogue: C/D map col=lane&15, row=(lane>>4)*4+r
#pragma unroll
  for (int mi = 0; mi < 4; ++mi)
#pragma unroll
    for (int ni = 0; ni < 4; ++ni)
#pragma unroll
      for (int r = 0; r < 4; ++r) {
        if constexpr (!LAYER1) {
          const int m_loc = wr * 64 + mi * 16 + (g << 2) + r;
          const int co = co0 + wc * 64 + ni * 16 + li;
          const size_t m = (size_t)bx * 128 + m_loc;
          gates[m * 256 + co] = (__bf16)(acc[mi][ni][r] + bias[co]);
        } else {
          const int co = co0 + wc * 64 + ni * 16 + (g << 2) + r;
          const int m_loc = wr * 64 + mi * 16 + li;
          const int m = bx * 128 + m_loc;
          const int nimg = m >> 10, p = m & 1023;
          gates[((size_t)nimg * 256 + co) * 1024 + p] =
              (__bf16)(acc[mi][ni][r] + bias[co]);
        }
      }
}

// ---------------------------------------------------------------------------
// scan0: gates [m][256] bf16 -> h0T padded NHWC bf16 (64,34,34,64)
// thread = (b, p, c-quad): bf16x4 loads/stores (8B/lane). 256 blocks x 256.
// ---------------------------------------------------------------------------
__global__ __launch_bounds__(256) void scan0_k(const __bf16* __restrict__ gates,
                                               __bf16* __restrict__ h0T) {
  const int g = blockIdx.x * 256 + threadIdx.x;  // 4*1024*16
  const int c = (g & 15) * 4;
  const int p = (g >> 4) & 1023;
  const int b = g >> 14;
  const int h = p >> 5, w = p & 31;
  float cst[4] = {0.5f, 0.5f, 0.5f, 0.5f};
#pragma unroll 4
  for (int s = 0; s < 16; ++s) {
    const size_t base = ((size_t)((b * 16 + s) * 1024 + p)) * 256 + c;
    const bf16x4* gp = reinterpret_cast<const bf16x4*>(gates + base);
    const bf16x4 ig4 = gp[0], fg4 = gp[16], og4 = gp[32], cd4 = gp[48];
    bf16x4 hv4;
#pragma unroll
    for (int j = 0; j < 4; ++j) {
      const float it = sigf((float)ig4[j]), ft = sigf((float)fg4[j]);
      const float inv = 1.0f / (it + ft);
      const float cd_ = (float)cd4[j];
      const float gc = (cd_ >= 0.0f) ? (cd_ + 0.5f) : sigf(cd_);
      cst[j] = (ft * inv) * cst[j] + (it * inv) * gc;
      hv4[j] = (__bf16)(sigf((float)og4[j]) * cst[j]);
    }
    *reinterpret_cast<bf16x4*>(
        h0T + ((size_t)((b * 16 + s) * HP + h + 1) * HP + (w + 1)) * 64 + c) = hv4;
  }
}

// ---------------------------------------------------------------------------
// scan1: gates [n][256][1024] bf16 -> out fp32 (B,S,64,32,32)
// thread = (b, c, 4 pixels): bf16x4 loads (8B), float4 stores. 256 blocks.
// ---------------------------------------------------------------------------
__global__ __launch_bounds__(256) void scan1_k(const __bf16* __restrict__ gates,
                                               float* __restrict__ out) {
  const int g = blockIdx.x * 256 + threadIdx.x;  // 4*64*256
  const int p0 = (g & 255) * 4;
  const int c = (g >> 8) & 63;
  const int b = g >> 14;
  float cst[4] = {0.5f, 0.5f, 0.5f, 0.5f};
#pragma unroll 2
  for (int s = 0; s < 16; ++s) {
    const size_t base = ((size_t)(b * 16 + s) * 256 + c) * 1024 + p0;
    const bf16x4 ig4 = *reinterpret_cast<const bf16x4*>(gates + base);
    const bf16x4 fg4 = *reinterpret_cast<const bf16x4*>(gates + base + 64 * 1024);
    const bf16x4 og4 = *reinterpret_cast<const bf16x4*>(gates + base + 128 * 1024);
    const bf16x4 cd4 = *reinterpret_cast<const bf16x4*>(gates + base + 192 * 1024);
    f32x4 hv;
#pragma unroll
    for (int j = 0; j < 4; ++j) {
      const float it = sigf((float)ig4[j]), ft = sigf((float)fg4[j]);
      const float inv = 1.0f / (it + ft);
      const float cd_ = (float)cd4[j];
      const float gc = (cd_ >= 0.0f) ? (cd_ + 0.5f) : sigf(cd_);
      cst[j] = (ft * inv) * cst[j] + (it * inv) * gc;
      hv[j] = sigf((float)og4[j]) * cst[j];
    }
    *reinterpret_cast<f32x4*>(
        out + ((size_t)((b * 16 + s) * 64 + c)) * 1024 + p0) = hv;
  }
}

// ---------------------------------------------------------------------------
extern "C" void kernel_launch(void* const* d_in, const int* in_sizes, int n_in,
                              void* d_out, int out_size, void* d_ws,
                              size_t ws_size, hipStream_t stream) {
  const float* x = (const float*)d_in[0];   // (4,16,32,32,32)
  const float* w0 = (const float*)d_in[1];  // (256,32,3,3)
  const float* b0 = (const float*)d_in[2];  // (256)
  const float* w1 = (const float*)d_in[3];  // (256,64,3,3)
  const float* b1 = (const float*)d_in[4];  // (256)
  float* out = (float*)d_out;               // (4,16,64,32,32)

  char* ws = (char*)d_ws;
  const size_t XT_BYTES = (size_t)N_IMG * HP * HP * 32 * 2;
  const size_t H0_BYTES = (size_t)N_IMG * HP * HP * 64 * 2;
  const size_t W0T_BYTES = (size_t)256 * 9 * 32 * 2;
  const size_t W1T_BYTES = (size_t)256 * 9 * 64 * 2;
  __bf16* xT = (__bf16*)ws;
  __bf16* h0T = (__bf16*)(ws + XT_BYTES);
  __bf16* w0T = (__bf16*)(ws + XT_BYTES + H0_BYTES);
  __bf16* w1T = (__bf16*)(ws + XT_BYTES + H0_BYTES + W0T_BYTES);
  __bf16* gates = (__bf16*)(ws + XT_BYTES + H0_BYTES + W0T_BYTES + W1T_BYTES);
  (void)ws_size; (void)n_in; (void)in_sizes; (void)out_size;

  hipMemsetAsync(xT, 0, XT_BYTES, stream);
  hipMemsetAsync(h0T, 0, H0_BYTES, stream);

  pack_x_k<<<N_IMG * 32, 256, 0, stream>>>(x, xT);
  pack_w_k<32><<<(256 * 9 * 32 + 255) / 256, 256, 0, stream>>>(w0, w0T);
  pack_w_k<64><<<(256 * 9 * 64 + 255) / 256, 256, 0, stream>>>(w1, w1T);

  // layer 0
  conv_gemm_k<32, false><<<dim3(512, 2), 256, 0, stream>>>(xT, w0T, b0, gates);
  scan0_k<<<256, 256, 0, stream>>>(gates, h0T);
  // layer 1
  conv_gemm_k<64, true><<<dim3(512, 2), 256, 0, stream>>>(h0T, w1T, b1, gates);
  scan1_k<<<256, 256, 0, stream>>>(gates, out);
}